// Round 1
// baseline (275.290 us; speedup 1.0000x reference)
//
#include <hip/hip_runtime.h>
#include <hip/hip_bf16.h>
#include <cstdint>
#include <cstddef>

#define NN 10000
#define MAXDEG 128

// ---------------- zero per-column counters ----------------
__global__ __launch_bounds__(256) void zero_cnt(int* __restrict__ cnt) {
    int i = blockIdx.x * 256 + threadIdx.x;
    if (i < NN) cnt[i] = 0;
}

// ---------------- scan dense adjacency -> column-grouped CSR ----------------
// adj is row-major [NN][NN]; nonzero at (i,j) => edge src=i, dst=j.
// csr[j*MAXDEG + pos] = i, cnt[j] = in-degree of j (column count).
__global__ __launch_bounds__(256) void adj_scan(const float4* __restrict__ adj4,
                                                int total4,
                                                int* __restrict__ cnt,
                                                int* __restrict__ csr) {
    int idx = blockIdx.x * blockDim.x + threadIdx.x;
    int stride = gridDim.x * blockDim.x;
    for (int p = idx; p < total4; p += stride) {
        float4 v = adj4[p];
        if (v.x != 0.f || v.y != 0.f || v.z != 0.f || v.w != 0.f) {
            int lin = p * 4;  // < 1e8, fits int32
            #pragma unroll
            for (int c = 0; c < 4; ++c) {
                float f = (c == 0) ? v.x : (c == 1) ? v.y : (c == 2) ? v.z : v.w;
                if (f != 0.f) {
                    int l = lin + c;
                    int i = l / NN;        // row (src)
                    int j = l - i * NN;    // col (dst)
                    int pos = atomicAdd(&cnt[j], 1);
                    if (pos < MAXDEG) csr[j * MAXDEG + pos] = i;
                }
            }
        }
    }
}

// ---------------- norm = clip(deg,1)^-0.5 ----------------
__global__ __launch_bounds__(256) void norm_k(const int* __restrict__ cnt,
                                              float* __restrict__ nrm) {
    int i = blockIdx.x * 256 + threadIdx.x;
    if (i < NN) {
        float d = fmaxf((float)cnt[i], 1.0f);
        nrm[i] = 1.0f / sqrtf(d);
    }
}

// ---------------- sparse propagation ----------------
// out[j, dstOff..] = scale * nrm[j] * sum_{i in csr[j]} nrm[i] * Xcat[i, srcOff..]
//                    (- Xcat[j, 0..] if SUB)
// One wave per node; each lane owns 2 feature columns.
template<bool SUB>
__global__ __launch_bounds__(256) void prop_k(float* __restrict__ Xcat,
                                              const int* __restrict__ csr,
                                              const int* __restrict__ cnt,
                                              const float* __restrict__ nrm,
                                              int srcOff, int dstOff, float scale) {
    int j = blockIdx.x * 4 + (threadIdx.x >> 6);
    if (j >= NN) return;
    int lane = threadIdx.x & 63;
    int c = lane * 2;
    int cn = min(cnt[j], MAXDEG);
    const int* nb = csr + j * MAXDEG;
    float ax = 0.f, ay = 0.f;
    for (int e = 0; e < cn; ++e) {
        int i = nb[e];
        float w = nrm[i];
        const float2 h = *(const float2*)(Xcat + (size_t)i * 384 + srcOff + c);
        ax = fmaf(w, h.x, ax);
        ay = fmaf(w, h.y, ay);
    }
    float s = scale * nrm[j];
    float rx = s * ax, ry = s * ay;
    if (SUB) {
        const float2 x0 = *(const float2*)(Xcat + (size_t)j * 384 + c);
        rx -= x0.x;
        ry -= x0.y;
    }
    *(float2*)(Xcat + (size_t)j * 384 + dstOff + c) = make_float2(rx, ry);
}

// ---------------- f32 GEMM: out[M,N] = A[M,K] @ W[K,N] + bias, optional relu --
// W staged in LDS (K chunks of 128), A tile staged in LDS.
// 256 threads; thread computes RPG rows x 2 cols.
template<int K, int N, bool RELU>
__global__ __launch_bounds__(256) void gemm_bias(const float* __restrict__ A, int lda,
                                                 const float* __restrict__ W,
                                                 const float* __restrict__ bias,
                                                 float* __restrict__ out, int ldo,
                                                 int M) {
    constexpr int BM = 32, KC = 128;
    constexpr int COLS2 = N / 2;      // 64 or 32
    constexpr int GR = 256 / COLS2;   // 4 or 8 row groups
    constexpr int RPG = BM / GR;      // 8 or 4 rows per thread
    __shared__ float Wl[KC * N];
    __shared__ float Al[BM * KC];

    int t = threadIdx.x;
    int r0 = blockIdx.x * BM;
    int c2 = t % COLS2;
    int g = t / COLS2;

    float2 acc[RPG];
    #pragma unroll
    for (int i = 0; i < RPG; ++i) acc[i] = make_float2(0.f, 0.f);

    for (int kk = 0; kk < K; kk += KC) {
        __syncthreads();
        // stage W chunk [KC][N] (contiguous in W)
        #pragma unroll
        for (int i = 0; i < KC * N / 4 / 256; ++i) {
            int idx = t + i * 256;
            ((float4*)Wl)[idx] = ((const float4*)(W + (size_t)kk * N))[idx];
        }
        // stage A tile [BM][KC]
        #pragma unroll
        for (int i = 0; i < BM * KC / 4 / 256; ++i) {
            int idx = t + i * 256;
            int row = idx / (KC / 4);
            int cf = idx % (KC / 4);
            float4 v = make_float4(0.f, 0.f, 0.f, 0.f);
            if (r0 + row < M)
                v = *(const float4*)(A + (size_t)(r0 + row) * lda + kk + cf * 4);
            *(float4*)(Al + row * KC + cf * 4) = v;
        }
        __syncthreads();

        for (int k = 0; k < KC; k += 4) {
            float4 av[RPG];
            #pragma unroll
            for (int rr = 0; rr < RPG; ++rr)
                av[rr] = *(const float4*)(Al + (g * RPG + rr) * KC + k);
            #pragma unroll
            for (int k2 = 0; k2 < 4; ++k2) {
                float2 wv = *(const float2*)(Wl + (k + k2) * N + c2 * 2);
                #pragma unroll
                for (int rr = 0; rr < RPG; ++rr) {
                    float a = (k2 == 0) ? av[rr].x : (k2 == 1) ? av[rr].y
                              : (k2 == 2) ? av[rr].z : av[rr].w;
                    acc[rr].x = fmaf(a, wv.x, acc[rr].x);
                    acc[rr].y = fmaf(a, wv.y, acc[rr].y);
                }
            }
        }
    }

    float2 bv = *(const float2*)(bias + c2 * 2);
    #pragma unroll
    for (int rr = 0; rr < RPG; ++rr) {
        int r = r0 + g * RPG + rr;
        if (r < M) {
            float2 v = acc[rr];
            v.x += bv.x;
            v.y += bv.y;
            if (RELU) { v.x = fmaxf(v.x, 0.f); v.y = fmaxf(v.y, 0.f); }
            *(float2*)(out + (size_t)r * ldo + c2 * 2) = v;
        }
    }
}

extern "C" void kernel_launch(void* const* d_in, const int* in_sizes, int n_in,
                              void* d_out, int out_size, void* d_ws, size_t ws_size,
                              hipStream_t stream) {
    const float* x      = (const float*)d_in[0];   // [10000,256]
    const float* adj    = (const float*)d_in[1];   // [10000,10000]
    const float* W_in   = (const float*)d_in[2];   // [256,128]
    const float* b_in   = (const float*)d_in[3];   // [128]
    const float* W_cheb = (const float*)d_in[4];   // [384,128]
    const float* b_cheb = (const float*)d_in[5];   // [128]
    const float* W_out  = (const float*)d_in[6];   // [128,64]
    const float* b_out  = (const float*)d_in[7];   // [64]
    float* out = (float*)d_out;                    // [10000,64]

    // workspace carve (all 256B-aligned)
    char* ws = (char*)d_ws;
    int*   cnt  = (int*)(ws + 0);            //  40,000 B
    float* nrm  = (float*)(ws + 40960);      //  40,000 B
    int*   csr  = (int*)(ws + 81920);        //  5,120,000 B
    float* Xcat = (float*)(ws + 5201920);    // 15,360,000 B  [10000][384] = X0|X1|X2
    float* hc   = (float*)(ws + 20561920);   //  5,120,000 B  [10000][128]

    int adj_total = in_sizes[1];             // 100,000,000

    zero_cnt<<<(NN + 255) / 256, 256, 0, stream>>>(cnt);
    adj_scan<<<2048, 256, 0, stream>>>((const float4*)adj, adj_total / 4, cnt, csr);
    norm_k<<<(NN + 255) / 256, 256, 0, stream>>>(cnt, nrm);

    int gblk = (NN + 31) / 32;
    // X0 = relu(x @ W_in + b_in) -> Xcat[:, 0:128]
    gemm_bias<256, 128, true><<<gblk, 256, 0, stream>>>(x, 256, W_in, b_in, Xcat, 384, NN);
    // X1 = -prop(X0) -> Xcat[:, 128:256]
    prop_k<false><<<(NN + 3) / 4, 256, 0, stream>>>(Xcat, csr, cnt, nrm, 0, 128, -1.0f);
    // X2 = -2*prop(X1) - X0 -> Xcat[:, 256:384]
    prop_k<true><<<(NN + 3) / 4, 256, 0, stream>>>(Xcat, csr, cnt, nrm, 128, 256, -2.0f);
    // hc = relu(Xcat @ W_cheb + b_cheb)
    gemm_bias<384, 128, true><<<gblk, 256, 0, stream>>>(Xcat, 384, W_cheb, b_cheb, hc, 128, NN);
    // out = hc @ W_out + b_out
    gemm_bias<128, 64, false><<<gblk, 256, 0, stream>>>(hc, 128, W_out, b_out, out, 64, NN);
}

// Round 2
// 270.265 us; speedup vs baseline: 1.0186x; 1.0186x over previous
//
#include <hip/hip_runtime.h>
#include <hip/hip_bf16.h>
#include <cstdint>
#include <cstddef>

#define NN 10000
#define MAXDEG 128
#define LDX 384   // Xcat leading dim (bf16 elems): X0|X1|X2

__device__ __forceinline__ float bf2f(unsigned short u) {
    unsigned int x = ((unsigned int)u) << 16;
    union { unsigned int i; float f; } c; c.i = x; return c.f;
}
__device__ __forceinline__ unsigned short f2bf(float f) {
    union { float f; unsigned int i; } c; c.f = f;
    unsigned int x = c.i;
    return (unsigned short)((x + 0x7fffu + ((x >> 16) & 1u)) >> 16);
}

// ---------------- zero per-column counters ----------------
__global__ __launch_bounds__(256) void zero_cnt(int* __restrict__ cnt) {
    int i = blockIdx.x * 256 + threadIdx.x;
    if (i < NN) cnt[i] = 0;
}

// ---------------- scan dense adjacency -> column-grouped CSR ----------------
__global__ __launch_bounds__(256) void adj_scan(const float4* __restrict__ adj4,
                                                int total4,
                                                int* __restrict__ cnt,
                                                int* __restrict__ csr) {
    int idx = blockIdx.x * blockDim.x + threadIdx.x;
    int stride = gridDim.x * blockDim.x;
    for (int p = idx; p < total4; p += stride) {
        float4 v = adj4[p];
        if (v.x != 0.f || v.y != 0.f || v.z != 0.f || v.w != 0.f) {
            int lin = p * 4;
            #pragma unroll
            for (int c = 0; c < 4; ++c) {
                float f = (c == 0) ? v.x : (c == 1) ? v.y : (c == 2) ? v.z : v.w;
                if (f != 0.f) {
                    int l = lin + c;
                    int i = l / NN;        // row (src)
                    int j = l - i * NN;    // col (dst)
                    int pos = atomicAdd(&cnt[j], 1);
                    if (pos < MAXDEG) csr[j * MAXDEG + pos] = i;
                }
            }
        }
    }
}

// ---------------- sparse propagation (bf16 features, f32 accum) -------------
// X[j, dstOff..] = scale*nrm[j]*sum_i nrm[i]*X[i, srcOff..]  (- X[j,0..] if SUB)
template<bool SUB>
__global__ __launch_bounds__(256) void prop_k(unsigned short* __restrict__ X,
                                              const int* __restrict__ csr,
                                              const int* __restrict__ cnt,
                                              int srcOff, int dstOff, float scale) {
    int j = blockIdx.x * 4 + (threadIdx.x >> 6);
    if (j >= NN) return;
    int lane = threadIdx.x & 63;
    int cj = cnt[j];
    int cn = min(cj, MAXDEG);
    const int* nb = csr + j * MAXDEG;
    float ax = 0.f, ay = 0.f;
    for (int e = 0; e < cn; ++e) {
        int i = nb[e];
        float w = rsqrtf(fmaxf((float)cnt[i], 1.f));
        uint32_t h2 = *(const uint32_t*)(X + (size_t)i * LDX + srcOff + lane * 2);
        ax = fmaf(w, bf2f((unsigned short)h2), ax);
        ay = fmaf(w, bf2f((unsigned short)(h2 >> 16)), ay);
    }
    float s = scale * rsqrtf(fmaxf((float)cj, 1.f));
    float rx = s * ax, ry = s * ay;
    if (SUB) {
        uint32_t x0 = *(const uint32_t*)(X + (size_t)j * LDX + lane * 2);
        rx -= bf2f((unsigned short)x0);
        ry -= bf2f((unsigned short)(x0 >> 16));
    }
    uint32_t o = (uint32_t)f2bf(rx) | ((uint32_t)f2bf(ry) << 16);
    *(uint32_t*)(X + (size_t)j * LDX + dstOff + lane * 2) = o;
}

// ---------------- gemm_in: X0 = relu(x@W_in + b) -> bf16 Xcat[:,0:128] ------
__global__ __launch_bounds__(256) void gemm_in(const float* __restrict__ A,  // [NN,256]
                                               const float* __restrict__ W,  // [256,128]
                                               const float* __restrict__ bias,
                                               unsigned short* __restrict__ Xc,
                                               int M) {
    constexpr int K = 256, N = 128, BM = 32, KC = 128;
    constexpr int COLS2 = N / 2, GR = 256 / COLS2, RPG = BM / GR; // 64,4,8
    __shared__ float Wl[KC * N];
    __shared__ float Al[BM * KC];
    int t = threadIdx.x;
    int r0 = blockIdx.x * BM;
    int c2 = t % COLS2;
    int g = t / COLS2;

    float2 acc[RPG];
    #pragma unroll
    for (int i = 0; i < RPG; ++i) acc[i] = make_float2(0.f, 0.f);

    for (int kk = 0; kk < K; kk += KC) {
        __syncthreads();
        #pragma unroll
        for (int i = 0; i < KC * N / 4 / 256; ++i) {
            int idx = t + i * 256;
            ((float4*)Wl)[idx] = ((const float4*)(W + (size_t)kk * N))[idx];
        }
        #pragma unroll
        for (int i = 0; i < BM * KC / 4 / 256; ++i) {
            int idx = t + i * 256;
            int row = idx / (KC / 4);
            int cf = idx % (KC / 4);
            float4 v = make_float4(0.f, 0.f, 0.f, 0.f);
            if (r0 + row < M)
                v = *(const float4*)(A + (size_t)(r0 + row) * K + kk + cf * 4);
            *(float4*)(Al + row * KC + cf * 4) = v;
        }
        __syncthreads();
        for (int k = 0; k < KC; k += 4) {
            float4 av[RPG];
            #pragma unroll
            for (int rr = 0; rr < RPG; ++rr)
                av[rr] = *(const float4*)(Al + (g * RPG + rr) * KC + k);
            #pragma unroll
            for (int k2 = 0; k2 < 4; ++k2) {
                float2 wv = *(const float2*)(Wl + (k + k2) * N + c2 * 2);
                #pragma unroll
                for (int rr = 0; rr < RPG; ++rr) {
                    float a = (k2 == 0) ? av[rr].x : (k2 == 1) ? av[rr].y
                              : (k2 == 2) ? av[rr].z : av[rr].w;
                    acc[rr].x = fmaf(a, wv.x, acc[rr].x);
                    acc[rr].y = fmaf(a, wv.y, acc[rr].y);
                }
            }
        }
    }
    float2 bv = *(const float2*)(bias + c2 * 2);
    #pragma unroll
    for (int rr = 0; rr < RPG; ++rr) {
        int r = r0 + g * RPG + rr;
        if (r < M) {
            float vx = fmaxf(acc[rr].x + bv.x, 0.f);
            float vy = fmaxf(acc[rr].y + bv.y, 0.f);
            uint32_t o = (uint32_t)f2bf(vx) | ((uint32_t)f2bf(vy) << 16);
            *(uint32_t*)(Xc + (size_t)r * LDX + c2 * 2) = o;
        }
    }
}

// ------- fused: hc = relu(Xcat@W_cheb + b_cheb); out = hc@W_out + b_out -----
__global__ __launch_bounds__(256) void gemm_cheb_out(
        const unsigned short* __restrict__ A,   // bf16 [NN,384]
        const float* __restrict__ Wc,           // [384,128]
        const float* __restrict__ bc,           // [128]
        const float* __restrict__ Wo,           // [128,64]
        const float* __restrict__ bo,           // [64]
        float* __restrict__ out,                // [NN,64]
        int M) {
    constexpr int K = 384, N = 128, BM = 32, KC = 128;
    constexpr int COLS2 = N / 2, GR = 256 / COLS2, RPG = BM / GR; // 64,4,8
    __shared__ float smem[KC * N + BM * KC];    // 20480 floats = 80 KB
    float* Wl = smem;                           // [KC][N]
    float* Al = smem + KC * N;                  // [BM][KC]
    int t = threadIdx.x;
    int r0 = blockIdx.x * BM;
    int c2 = t % COLS2;
    int g = t / COLS2;

    float2 acc[RPG];
    #pragma unroll
    for (int i = 0; i < RPG; ++i) acc[i] = make_float2(0.f, 0.f);

    for (int kk = 0; kk < K; kk += KC) {
        __syncthreads();
        #pragma unroll
        for (int i = 0; i < KC * N / 4 / 256; ++i) {
            int idx = t + i * 256;
            ((float4*)Wl)[idx] = ((const float4*)(Wc + (size_t)kk * N))[idx];
        }
        // stage A tile: bf16 -> f32
        #pragma unroll
        for (int i = 0; i < BM * KC / 4 / 256; ++i) {  // 4 iters, 4 elems each
            int eidx = (t + i * 256) * 4;
            int row = eidx / KC;
            int col = eidx % KC;
            float4 v = make_float4(0.f, 0.f, 0.f, 0.f);
            if (r0 + row < M) {
                uint2 u = *(const uint2*)(A + (size_t)(r0 + row) * LDX + kk + col);
                v.x = bf2f((unsigned short)u.x);
                v.y = bf2f((unsigned short)(u.x >> 16));
                v.z = bf2f((unsigned short)u.y);
                v.w = bf2f((unsigned short)(u.y >> 16));
            }
            *(float4*)(Al + row * KC + col) = v;
        }
        __syncthreads();
        for (int k = 0; k < KC; k += 4) {
            float4 av[RPG];
            #pragma unroll
            for (int rr = 0; rr < RPG; ++rr)
                av[rr] = *(const float4*)(Al + (g * RPG + rr) * KC + k);
            #pragma unroll
            for (int k2 = 0; k2 < 4; ++k2) {
                float2 wv = *(const float2*)(Wl + (k + k2) * N + c2 * 2);
                #pragma unroll
                for (int rr = 0; rr < RPG; ++rr) {
                    float a = (k2 == 0) ? av[rr].x : (k2 == 1) ? av[rr].y
                              : (k2 == 2) ? av[rr].z : av[rr].w;
                    acc[rr].x = fmaf(a, wv.x, acc[rr].x);
                    acc[rr].y = fmaf(a, wv.y, acc[rr].y);
                }
            }
        }
    }

    // ---- phase 2: out tile = relu(hc) @ Wo + bo ----
    __syncthreads();                       // everyone done reading Wl/Al
    float* hcL  = smem;                    // [BM][128]  (4096 f)
    float* WoL  = smem + BM * N;           // [128][64]  (8192 f)
    float2 bv = *(const float2*)(bc + c2 * 2);
    #pragma unroll
    for (int rr = 0; rr < RPG; ++rr) {
        int row = g * RPG + rr;
        float vx = fmaxf(acc[rr].x + bv.x, 0.f);
        float vy = fmaxf(acc[rr].y + bv.y, 0.f);
        *(float2*)(hcL + row * N + c2 * 2) = make_float2(vx, vy);
    }
    #pragma unroll
    for (int i = 0; i < 128 * 64 / 4 / 256; ++i) {   // 8 float4 per thread
        int idx = t + i * 256;
        ((float4*)WoL)[idx] = ((const float4*)Wo)[idx];
    }
    __syncthreads();

    int c32 = t & 31;          // 2 out cols per thread
    int g2 = t >> 5;           // 8 row groups, 4 rows each
    float2 a2[4];
    #pragma unroll
    for (int i = 0; i < 4; ++i) a2[i] = make_float2(0.f, 0.f);
    for (int k = 0; k < 128; k += 4) {
        float4 hv[4];
        #pragma unroll
        for (int rr = 0; rr < 4; ++rr)
            hv[rr] = *(const float4*)(hcL + (g2 * 4 + rr) * N + k);
        #pragma unroll
        for (int k2 = 0; k2 < 4; ++k2) {
            float2 wv = *(const float2*)(WoL + (k + k2) * 64 + c32 * 2);
            #pragma unroll
            for (int rr = 0; rr < 4; ++rr) {
                float a = (k2 == 0) ? hv[rr].x : (k2 == 1) ? hv[rr].y
                          : (k2 == 2) ? hv[rr].z : hv[rr].w;
                a2[rr].x = fmaf(a, wv.x, a2[rr].x);
                a2[rr].y = fmaf(a, wv.y, a2[rr].y);
            }
        }
    }
    float2 bov = *(const float2*)(bo + c32 * 2);
    #pragma unroll
    for (int rr = 0; rr < 4; ++rr) {
        int r = r0 + g2 * 4 + rr;
        if (r < M) {
            float2 v = make_float2(a2[rr].x + bov.x, a2[rr].y + bov.y);
            *(float2*)(out + (size_t)r * 64 + c32 * 2) = v;
        }
    }
}

extern "C" void kernel_launch(void* const* d_in, const int* in_sizes, int n_in,
                              void* d_out, int out_size, void* d_ws, size_t ws_size,
                              hipStream_t stream) {
    const float* x      = (const float*)d_in[0];   // [10000,256]
    const float* adj    = (const float*)d_in[1];   // [10000,10000]
    const float* W_in   = (const float*)d_in[2];   // [256,128]
    const float* b_in   = (const float*)d_in[3];   // [128]
    const float* W_cheb = (const float*)d_in[4];   // [384,128]
    const float* b_cheb = (const float*)d_in[5];   // [128]
    const float* W_out  = (const float*)d_in[6];   // [128,64]
    const float* b_out  = (const float*)d_in[7];   // [64]
    float* out = (float*)d_out;                    // [10000,64]

    char* ws = (char*)d_ws;
    int*            cnt = (int*)(ws + 0);                 //  40,000 B
    int*            csr = (int*)(ws + 40960);             //   5.12 MB
    unsigned short* Xc  = (unsigned short*)(ws + 5160960);//   7.68 MB  bf16 [NN][384]

    int adj_total = in_sizes[1];   // 100,000,000

    zero_cnt<<<(NN + 255) / 256, 256, 0, stream>>>(cnt);
    adj_scan<<<4096, 256, 0, stream>>>((const float4*)adj, adj_total / 4, cnt, csr);
    gemm_in<<<(NN + 31) / 32, 256, 0, stream>>>(x, W_in, b_in, Xc, NN);
    prop_k<false><<<(NN + 3) / 4, 256, 0, stream>>>(Xc, csr, cnt, 0, 128, -1.0f);
    prop_k<true><<<(NN + 3) / 4, 256, 0, stream>>>(Xc, csr, cnt, 128, 256, -2.0f);
    gemm_cheb_out<<<(NN + 31) / 32, 256, 0, stream>>>(Xc, W_cheb, b_cheb, W_out, b_out, out, NN);
}

// Round 3
// 238.480 us; speedup vs baseline: 1.1544x; 1.1333x over previous
//
#include <hip/hip_runtime.h>
#include <hip/hip_bf16.h>
#include <cstdint>
#include <cstddef>

#define NN 10000
#define MAXDEG 128
#define LDX 384

#define GEMM_BLKS 313
#define CONV_BLK  1
#define SCAN_BLKS 3072
#define FAT_BLKS  (GEMM_BLKS + CONV_BLK + SCAN_BLKS)

typedef __attribute__((ext_vector_type(8))) short bf16x8;
typedef __attribute__((ext_vector_type(4))) float f32x4;

__device__ __forceinline__ float bf2f(unsigned short u) {
    union { unsigned int i; float f; } c; c.i = ((unsigned int)u) << 16; return c.f;
}
__device__ __forceinline__ unsigned short f2bf(float f) {
    union { float f; unsigned int i; } c; c.f = f;
    unsigned int x = c.i;
    return (unsigned short)((x + 0x7fffu + ((x >> 16) & 1u)) >> 16);
}

// ---------------- fat kernel: gemm_in (blocks 0..312) | convert (313) | scan --
__global__ __launch_bounds__(256) void fat_scan_gemm(
        const float4* __restrict__ adj4, int total4,
        int* __restrict__ cnt, int* __restrict__ csr,
        const float* __restrict__ x, const float* __restrict__ W_in,
        const float* __restrict__ b_in,
        const float* __restrict__ W_cheb, const float* __restrict__ W_out,
        unsigned short* __restrict__ Xc,
        unsigned short* __restrict__ Wtc, unsigned short* __restrict__ Wto) {
    __shared__ float smem[10240];   // 40 KB
    int bid = blockIdx.x;
    int t = threadIdx.x;

    if (bid < GEMM_BLKS) {
        // ---- gemm_in: X0 = relu(x @ W_in + b_in) -> bf16 Xc[:,0:128] ----
        constexpr int K = 256, N = 128, BM = 32, KC = 64;
        float* Wl = smem;            // [KC][N]  8192 f
        float* Al = smem + KC * N;   // [BM][KC] 2048 f
        int r0 = bid * BM;
        int c2 = t & 63;             // col pair 0..63
        int g  = t >> 6;             // row group 0..3 (8 rows each)
        float2 acc[8];
        #pragma unroll
        for (int i = 0; i < 8; ++i) acc[i] = make_float2(0.f, 0.f);

        for (int kk = 0; kk < K; kk += KC) {
            __syncthreads();
            #pragma unroll
            for (int i = 0; i < KC * N / 4 / 256; ++i) {   // 8
                int idx = t + i * 256;
                ((float4*)Wl)[idx] = ((const float4*)(W_in + (size_t)kk * N))[idx];
            }
            #pragma unroll
            for (int i = 0; i < BM * KC / 4 / 256; ++i) {  // 2
                int idx = t + i * 256;
                int row = idx >> 4;           // /(KC/4)
                int cf  = idx & 15;
                float4 v = make_float4(0.f, 0.f, 0.f, 0.f);
                if (r0 + row < NN)
                    v = *(const float4*)(x + (size_t)(r0 + row) * K + kk + cf * 4);
                *(float4*)(Al + row * KC + cf * 4) = v;
            }
            __syncthreads();
            for (int k = 0; k < KC; k += 4) {
                float4 av[8];
                #pragma unroll
                for (int rr = 0; rr < 8; ++rr)
                    av[rr] = *(const float4*)(Al + (g * 8 + rr) * KC + k);
                #pragma unroll
                for (int k2 = 0; k2 < 4; ++k2) {
                    float2 wv = *(const float2*)(Wl + (k + k2) * N + c2 * 2);
                    #pragma unroll
                    for (int rr = 0; rr < 8; ++rr) {
                        float a = (k2 == 0) ? av[rr].x : (k2 == 1) ? av[rr].y
                                  : (k2 == 2) ? av[rr].z : av[rr].w;
                        acc[rr].x = fmaf(a, wv.x, acc[rr].x);
                        acc[rr].y = fmaf(a, wv.y, acc[rr].y);
                    }
                }
            }
        }
        float2 bv = *(const float2*)(b_in + c2 * 2);
        #pragma unroll
        for (int rr = 0; rr < 8; ++rr) {
            int r = r0 + g * 8 + rr;
            if (r < NN) {
                float vx = fmaxf(acc[rr].x + bv.x, 0.f);
                float vy = fmaxf(acc[rr].y + bv.y, 0.f);
                uint32_t o = (uint32_t)f2bf(vx) | ((uint32_t)f2bf(vy) << 16);
                *(uint32_t*)(Xc + (size_t)r * LDX + c2 * 2) = o;
            }
        }
    } else if (bid == GEMM_BLKS) {
        // ---- one-time weight transpose+convert ----
        for (int idx = t; idx < 384 * 128; idx += 256) {
            int k = idx >> 7, c = idx & 127;
            Wtc[c * 384 + k] = f2bf(W_cheb[idx]);
        }
        for (int idx = t; idx < 128 * 64; idx += 256) {
            int k = idx >> 6, c = idx & 63;
            Wto[c * 128 + k] = f2bf(W_out[idx]);
        }
    } else {
        // ---- adjacency scan -> column-grouped CSR ----
        int sid = bid - (GEMM_BLKS + CONV_BLK);
        int idx = sid * 256 + t;
        int stride = SCAN_BLKS * 256;
        for (int p = idx; p < total4; p += stride) {
            float4 v = adj4[p];
            if (v.x != 0.f || v.y != 0.f || v.z != 0.f || v.w != 0.f) {
                int lin = p * 4;
                #pragma unroll
                for (int c = 0; c < 4; ++c) {
                    float f = (c == 0) ? v.x : (c == 1) ? v.y : (c == 2) ? v.z : v.w;
                    if (f != 0.f) {
                        int l = lin + c;
                        int i = l / NN;
                        int j = l - i * NN;
                        int pos = atomicAdd(&cnt[j], 1);
                        if (pos < MAXDEG) csr[j * MAXDEG + pos] = i;
                    }
                }
            }
        }
    }
}

// ---------------- sparse propagation (bf16, unroll-2, indep chains) ---------
template<bool SUB>
__global__ __launch_bounds__(256) void prop_k(unsigned short* __restrict__ X,
                                              const int* __restrict__ csr,
                                              const int* __restrict__ cnt,
                                              int srcOff, int dstOff, float scale) {
    int j = blockIdx.x * 4 + (threadIdx.x >> 6);
    if (j >= NN) return;
    int lane = threadIdx.x & 63;
    int cj = cnt[j];
    int cn = min(cj, MAXDEG);
    const int* nb = csr + j * MAXDEG;
    float ax0 = 0.f, ay0 = 0.f, ax1 = 0.f, ay1 = 0.f;
    int e = 0;
    for (; e + 2 <= cn; e += 2) {
        int i0 = nb[e], i1 = nb[e + 1];
        int c0 = cnt[i0], c1 = cnt[i1];
        uint32_t h0 = *(const uint32_t*)(X + (size_t)i0 * LDX + srcOff + lane * 2);
        uint32_t h1 = *(const uint32_t*)(X + (size_t)i1 * LDX + srcOff + lane * 2);
        float w0 = rsqrtf(fmaxf((float)c0, 1.f));
        float w1 = rsqrtf(fmaxf((float)c1, 1.f));
        ax0 = fmaf(w0, bf2f((unsigned short)h0), ax0);
        ay0 = fmaf(w0, bf2f((unsigned short)(h0 >> 16)), ay0);
        ax1 = fmaf(w1, bf2f((unsigned short)h1), ax1);
        ay1 = fmaf(w1, bf2f((unsigned short)(h1 >> 16)), ay1);
    }
    if (e < cn) {
        int i0 = nb[e];
        float w0 = rsqrtf(fmaxf((float)cnt[i0], 1.f));
        uint32_t h0 = *(const uint32_t*)(X + (size_t)i0 * LDX + srcOff + lane * 2);
        ax0 = fmaf(w0, bf2f((unsigned short)h0), ax0);
        ay0 = fmaf(w0, bf2f((unsigned short)(h0 >> 16)), ay0);
    }
    float s = scale * rsqrtf(fmaxf((float)cj, 1.f));
    float rx = s * (ax0 + ax1), ry = s * (ay0 + ay1);
    if (SUB) {
        uint32_t x0 = *(const uint32_t*)(X + (size_t)j * LDX + lane * 2);
        rx -= bf2f((unsigned short)x0);
        ry -= bf2f((unsigned short)(x0 >> 16));
    }
    uint32_t o = (uint32_t)f2bf(rx) | ((uint32_t)f2bf(ry) << 16);
    *(uint32_t*)(X + (size_t)j * LDX + dstOff + lane * 2) = o;
}

// -------- MFMA fused: hc = relu(Xc@Wc + bc); out = hc@Wo + bo ---------------
// block: 32 rows x 128 cols, 4 waves. Phase1 wave w: cols w*32..+32.
__global__ __launch_bounds__(256) void cheb_out_mfma(
        const unsigned short* __restrict__ Xc,   // [NN][384] bf16
        const unsigned short* __restrict__ Wtc,  // [128][384] bf16 (W_cheb^T)
        const float* __restrict__ bc,
        const unsigned short* __restrict__ Wto,  // [64][128] bf16 (W_out^T)
        const float* __restrict__ bo,
        float* __restrict__ out) {
    __shared__ unsigned short hcL[32][136];      // +8 pad -> 2-way banks only
    int t = threadIdx.x;
    int w = t >> 6, lane = t & 63;
    int r0 = blockIdx.x * 32;
    int lr = lane & 15;
    int kg = lane >> 4;

    f32x4 acc[2][2] = {};   // [row tile m][col tile n]
    for (int k0 = 0; k0 < 384; k0 += 32) {
        bf16x8 a[2], b[2];
        #pragma unroll
        for (int m = 0; m < 2; ++m) {
            int row = r0 + m * 16 + lr;
            row = min(row, NN - 1);
            a[m] = *(const bf16x8*)(Xc + (size_t)row * LDX + k0 + kg * 8);
        }
        #pragma unroll
        for (int n = 0; n < 2; ++n) {
            int col = w * 32 + n * 16 + lr;
            b[n] = *(const bf16x8*)(Wtc + (size_t)col * 384 + k0 + kg * 8);
        }
        #pragma unroll
        for (int m = 0; m < 2; ++m)
            #pragma unroll
            for (int n = 0; n < 2; ++n)
                acc[m][n] = __builtin_amdgcn_mfma_f32_16x16x32_bf16(a[m], b[n], acc[m][n], 0, 0, 0);
    }
    // bias + relu -> bf16 -> LDS
    #pragma unroll
    for (int m = 0; m < 2; ++m) {
        #pragma unroll
        for (int n = 0; n < 2; ++n) {
            int col = w * 32 + n * 16 + lr;
            float bv = bc[col];
            #pragma unroll
            for (int r = 0; r < 4; ++r) {
                int row = m * 16 + kg * 4 + r;
                hcL[row][col] = f2bf(fmaxf(acc[m][n][r] + bv, 0.f));
            }
        }
    }
    __syncthreads();
    // phase 2: wave w -> row tile rt=w>>1, col half ch=w&1 (2 col tiles)
    int rt = w >> 1, ch = w & 1;
    f32x4 a2[2] = {};
    for (int k0 = 0; k0 < 128; k0 += 32) {
        bf16x8 af = *(const bf16x8*)(&hcL[rt * 16 + lr][k0 + kg * 8]);
        #pragma unroll
        for (int n = 0; n < 2; ++n) {
            int col = ch * 32 + n * 16 + lr;
            bf16x8 bf_ = *(const bf16x8*)(Wto + (size_t)col * 128 + k0 + kg * 8);
            a2[n] = __builtin_amdgcn_mfma_f32_16x16x32_bf16(af, bf_, a2[n], 0, 0, 0);
        }
    }
    #pragma unroll
    for (int n = 0; n < 2; ++n) {
        int col = ch * 32 + n * 16 + lr;
        float bv = bo[col];
        #pragma unroll
        for (int r = 0; r < 4; ++r) {
            int row = r0 + rt * 16 + kg * 4 + r;
            if (row < NN) out[(size_t)row * 64 + col] = a2[n][r] + bv;
        }
    }
}

extern "C" void kernel_launch(void* const* d_in, const int* in_sizes, int n_in,
                              void* d_out, int out_size, void* d_ws, size_t ws_size,
                              hipStream_t stream) {
    const float* x      = (const float*)d_in[0];
    const float* adj    = (const float*)d_in[1];
    const float* W_in   = (const float*)d_in[2];
    const float* b_in   = (const float*)d_in[3];
    const float* W_cheb = (const float*)d_in[4];
    const float* b_cheb = (const float*)d_in[5];
    const float* W_out  = (const float*)d_in[6];
    const float* b_out  = (const float*)d_in[7];
    float* out = (float*)d_out;

    char* ws = (char*)d_ws;
    int*            cnt = (int*)(ws + 0);                   // 40,000 B
    int*            csr = (int*)(ws + 40960);               // 5.12 MB
    unsigned short* Xc  = (unsigned short*)(ws + 5160960);  // 7.68 MB
    unsigned short* Wtc = (unsigned short*)(ws + 12845056); // 98,304 B
    unsigned short* Wto = (unsigned short*)(ws + 12943360); // 16,384 B

    int adj_total = in_sizes[1];

    hipMemsetAsync(cnt, 0, NN * sizeof(int), stream);
    fat_scan_gemm<<<FAT_BLKS, 256, 0, stream>>>(
        (const float4*)adj, adj_total / 4, cnt, csr,
        x, W_in, b_in, W_cheb, W_out, Xc, Wtc, Wto);
    prop_k<false><<<(NN + 3) / 4, 256, 0, stream>>>(Xc, csr, cnt, 0, 128, -1.0f);
    prop_k<true><<<(NN + 3) / 4, 256, 0, stream>>>(Xc, csr, cnt, 128, 256, -2.0f);
    cheb_out_mfma<<<(NN + 31) / 32, 256, 0, stream>>>(Xc, Wtc, b_cheb, Wto, b_out, out);
}